// Round 1
// baseline (518.431 us; speedup 1.0000x reference)
//
#include <hip/hip_runtime.h>
#include <math.h>

#define BB   32
#define HH   32
#define WWW  32
#define DIN  1024
#define DE   64
#define KK   8192
#define NN   512            // B*S flat rows
#define EPSF 1e-12f

// d_out layout (floats): decoded | perplexity | codebooks_used | indices
#define OUT_PERP   33554432
#define OUT_COUNTS 33554433
#define OUT_IDX    33562625

// ws layout (floats)
#define WS_POOLED 0
#define WS_Y      524288
#define WS_CBN    1048576

// ---------------------------------------------------------------------------
// K1: blocks [0,512): pooled[n][c] = mean over 8x8 spatial block of (t1-t0)
//     blocks [512,544): codebook squared norms + zero counts output
// ---------------------------------------------------------------------------
__global__ __launch_bounds__(256) void k_pool_cbn(
    const float* __restrict__ t0, const float* __restrict__ t1,
    const float* __restrict__ codebooks,
    float* __restrict__ pooled, float* __restrict__ cbn,
    float* __restrict__ counts)
{
  int t = threadIdx.x;
  int n = blockIdx.x;
  if (n >= NN) {
    int k = (n - NN) * 256 + t;
    const float4* c = (const float4*)(codebooks + (size_t)k * DE);
    float s = 0.f;
    #pragma unroll
    for (int i = 0; i < DE / 4; ++i) {
      float4 v = c[i];
      s = fmaf(v.x, v.x, fmaf(v.y, v.y, fmaf(v.z, v.z, fmaf(v.w, v.w, s))));
    }
    cbn[k] = s;
    counts[k] = 0.f;     // d_out counts region zeroed before k_vq atomics
    return;
  }
  int b = n >> 4, gi = (n >> 2) & 3, gj = n & 3;
  size_t base = (((size_t)b * HH + gi * 8) * WWW + gj * 8) * DIN;
  const float4* p0 = (const float4*)(t0 + base) + t;
  const float4* p1 = (const float4*)(t1 + base) + t;
  float ax = 0.f, ay = 0.f, az = 0.f, aw = 0.f;
  #pragma unroll 2
  for (int r = 0; r < 8; ++r) {
    #pragma unroll
    for (int c = 0; c < 8; ++c) {
      size_t off = ((size_t)r * WWW + c) * (DIN / 4);
      float4 u = p1[off];
      float4 v = p0[off];
      ax += u.x - v.x; ay += u.y - v.y; az += u.z - v.z; aw += u.w - v.w;
    }
  }
  const float inv = 1.f / 64.f;
  float4 o = make_float4(ax * inv, ay * inv, az * inv, aw * inv);
  ((float4*)(pooled + (size_t)n * DIN))[t] = o;
}

// ---------------------------------------------------------------------------
// K2: per block: 4 flat rows. encode -> VQ argmin -> NSVQ noise sub -> W_out
// ---------------------------------------------------------------------------
__device__ __forceinline__ void upd_min(unsigned long long& best, float e, int k) {
  e = fmaxf(e, 0.f);  // dist >= 0; keeps uint ordering of float bits monotone
  unsigned long long p =
      ((unsigned long long)__float_as_uint(e) << 32) | (unsigned int)k;
  best = (p < best) ? p : best;
}

__global__ __launch_bounds__(256) void k_vq(
    const float* __restrict__ pooled, const float* __restrict__ cbn,
    const float* __restrict__ noise, const float* __restrict__ codebooks,
    const float* __restrict__ W_in, const float* __restrict__ b_in,
    const float* __restrict__ W_out, const float* __restrict__ b_out,
    float* __restrict__ Y, float* __restrict__ counts,
    float* __restrict__ idx_out)
{
  __shared__ float s_pool[4][DIN];   // 16 KB
  __shared__ float s_f[4][DE];
  __shared__ float s_q[4][DE];
  __shared__ float s_fn[4];
  __shared__ unsigned long long s_min[4];
  int t = threadIdx.x;
  int n0 = blockIdx.x * 4;

  #pragma unroll
  for (int r = 0; r < 4; ++r)
    ((float4*)s_pool[r])[t] = ((const float4*)(pooled + (size_t)(n0 + r) * DIN))[t];
  if (t < 4) s_min[t] = ~0ull;
  __syncthreads();

  // encode: thread t -> (row r, dim d); dot(pooled_row, W_in[d,:]) + b_in
  {
    int r = t >> 6, d = t & 63;
    const float4* w = (const float4*)(W_in + (size_t)d * DIN);
    const float4* p = (const float4*)s_pool[r];
    float acc = 0.f;
    for (int c = 0; c < DIN / 4; ++c) {
      float4 wv = w[c], pv = p[c];
      acc = fmaf(pv.x, wv.x, acc); acc = fmaf(pv.y, wv.y, acc);
      acc = fmaf(pv.z, wv.z, acc); acc = fmaf(pv.w, wv.w, acc);
    }
    s_f[r][d] = acc + b_in[d];
  }
  __syncthreads();

  if (t < 4) {
    float s = 0.f;
    for (int i = 0; i < DE; ++i) { float v = s_f[t][i]; s = fmaf(v, v, s); }
    s_fn[t] = s;
  }
  __syncthreads();

  float fn0 = s_fn[0], fn1 = s_fn[1], fn2 = s_fn[2], fn3 = s_fn[3];
  const float4* sf0 = (const float4*)s_f[0];
  const float4* sf1 = (const float4*)s_f[1];
  const float4* sf2 = (const float4*)s_f[2];
  const float4* sf3 = (const float4*)s_f[3];

  unsigned long long b0 = ~0ull, b1 = ~0ull, b2 = ~0ull, b3 = ~0ull;
  for (int kk = t; kk < KK / 2; kk += 256) {
    int k0 = kk * 2;
    const float4* c0 = (const float4*)(codebooks + (size_t)k0 * DE);
    float d00 = 0, d01 = 0, d02 = 0, d03 = 0;
    float d10 = 0, d11 = 0, d12 = 0, d13 = 0;
    #pragma unroll
    for (int i = 0; i < DE / 4; ++i) {
      float4 a = c0[i];
      float4 bq = c0[i + 16];
      float4 f0 = sf0[i], f1 = sf1[i], f2 = sf2[i], f3 = sf3[i];
      d00 = fmaf(f0.x, a.x, fmaf(f0.y, a.y, fmaf(f0.z, a.z, fmaf(f0.w, a.w, d00))));
      d01 = fmaf(f1.x, a.x, fmaf(f1.y, a.y, fmaf(f1.z, a.z, fmaf(f1.w, a.w, d01))));
      d02 = fmaf(f2.x, a.x, fmaf(f2.y, a.y, fmaf(f2.z, a.z, fmaf(f2.w, a.w, d02))));
      d03 = fmaf(f3.x, a.x, fmaf(f3.y, a.y, fmaf(f3.z, a.z, fmaf(f3.w, a.w, d03))));
      d10 = fmaf(f0.x, bq.x, fmaf(f0.y, bq.y, fmaf(f0.z, bq.z, fmaf(f0.w, bq.w, d10))));
      d11 = fmaf(f1.x, bq.x, fmaf(f1.y, bq.y, fmaf(f1.z, bq.z, fmaf(f1.w, bq.w, d11))));
      d12 = fmaf(f2.x, bq.x, fmaf(f2.y, bq.y, fmaf(f2.z, bq.z, fmaf(f2.w, bq.w, d12))));
      d13 = fmaf(f3.x, bq.x, fmaf(f3.y, bq.y, fmaf(f3.z, bq.z, fmaf(f3.w, bq.w, d13))));
    }
    float cn0 = cbn[k0], cn1 = cbn[k0 + 1];
    upd_min(b0, fmaf(-2.f, d00, fn0 + cn0), k0);
    upd_min(b1, fmaf(-2.f, d01, fn1 + cn0), k0);
    upd_min(b2, fmaf(-2.f, d02, fn2 + cn0), k0);
    upd_min(b3, fmaf(-2.f, d03, fn3 + cn0), k0);
    upd_min(b0, fmaf(-2.f, d10, fn0 + cn1), k0 + 1);
    upd_min(b1, fmaf(-2.f, d11, fn1 + cn1), k0 + 1);
    upd_min(b2, fmaf(-2.f, d12, fn2 + cn1), k0 + 1);
    upd_min(b3, fmaf(-2.f, d13, fn3 + cn1), k0 + 1);
  }
  atomicMin(&s_min[0], b0);
  atomicMin(&s_min[1], b1);
  atomicMin(&s_min[2], b2);
  atomicMin(&s_min[3], b3);
  __syncthreads();

  // NSVQ: wave r handles row r (64 lanes = 64 dims)
  {
    int r = t >> 6, lane = t & 63;
    unsigned idx = (unsigned)(s_min[r] & 0xffffffffu);
    float f = s_f[r][lane];
    float hv = codebooks[(size_t)idx * DE + lane];
    float df = f - hv;
    float sd = df * df;
    float nz = noise[(size_t)(n0 + r) * DE + lane];
    float sn = nz * nz;
    #pragma unroll
    for (int m = 32; m > 0; m >>= 1) {
      sd += __shfl_xor(sd, m, 64);
      sn += __shfl_xor(sn, m, 64);
    }
    float scale = sqrtf(sd) / (sqrtf(sn) + EPSF);
    s_q[r][lane] = fmaf(scale, nz, f);
    if (lane == 0) {
      idx_out[n0 + r] = (float)idx;
      atomicAdd(&counts[idx], 1.0f);
    }
  }
  __syncthreads();

  // project out: Y[n][c] = dot(q[n], W_out[c,:]) + b_out[c]
  const float4* q0 = (const float4*)s_q[0];
  const float4* q1 = (const float4*)s_q[1];
  const float4* q2 = (const float4*)s_q[2];
  const float4* q3 = (const float4*)s_q[3];
  for (int j = 0; j < 4; ++j) {
    int c = t + 256 * j;
    const float4* w = (const float4*)(W_out + (size_t)c * DE);
    float a0 = 0, a1 = 0, a2 = 0, a3 = 0;
    #pragma unroll
    for (int i = 0; i < DE / 4; ++i) {
      float4 wv = w[i];
      float4 v0 = q0[i], v1 = q1[i], v2 = q2[i], v3 = q3[i];
      a0 = fmaf(v0.x, wv.x, fmaf(v0.y, wv.y, fmaf(v0.z, wv.z, fmaf(v0.w, wv.w, a0))));
      a1 = fmaf(v1.x, wv.x, fmaf(v1.y, wv.y, fmaf(v1.z, wv.z, fmaf(v1.w, wv.w, a1))));
      a2 = fmaf(v2.x, wv.x, fmaf(v2.y, wv.y, fmaf(v2.z, wv.z, fmaf(v2.w, wv.w, a2))));
      a3 = fmaf(v3.x, wv.x, fmaf(v3.y, wv.y, fmaf(v3.z, wv.z, fmaf(v3.w, wv.w, a3))));
    }
    float bo = b_out[c];
    Y[(size_t)(n0 + 0) * DIN + c] = a0 + bo;
    Y[(size_t)(n0 + 1) * DIN + c] = a1 + bo;
    Y[(size_t)(n0 + 2) * DIN + c] = a2 + bo;
    Y[(size_t)(n0 + 3) * DIN + c] = a3 + bo;
  }
}

// ---------------------------------------------------------------------------
// K3: blocks [0,1024): one (b,h) row -> bilinear upsample 32 pixels x 1024 ch
//     block 1024: perplexity from counts
// ---------------------------------------------------------------------------
__global__ __launch_bounds__(256) void k_decode(
    const float* __restrict__ Y, const float* __restrict__ counts,
    float* __restrict__ decoded, float* __restrict__ perp)
{
  int t = threadIdx.x;
  if (blockIdx.x == 1024) {
    __shared__ float red[256];
    float s = 0.f;
    for (int k = t; k < KK; k += 256) {
      float p = counts[k] * (1.0f / 512.0f);
      s += p * logf(p + EPSF);
    }
    red[t] = s;
    __syncthreads();
    for (int o = 128; o > 0; o >>= 1) {
      if (t < o) red[t] += red[t + o];
      __syncthreads();
    }
    if (t == 0) perp[0] = expf(-red[0]);
    return;
  }
  __shared__ float s_y[8][DIN];  // rows {y0,y1} x gx{0..3} : 32 KB
  int bh = blockIdx.x;
  int b = bh >> 5, h = bh & 31;
  float sy = (h + 0.5f) * 0.125f - 0.5f;
  int y0 = (int)floorf(sy);
  float fy = sy - (float)y0;
  int y1 = min(y0 + 1, 3);
  y0 = max(y0, 0);
  #pragma unroll
  for (int gx = 0; gx < 4; ++gx) {
    ((float4*)s_y[gx])[t]     = ((const float4*)(Y + (size_t)(b * 16 + y0 * 4 + gx) * DIN))[t];
    ((float4*)s_y[4 + gx])[t] = ((const float4*)(Y + (size_t)(b * 16 + y1 * 4 + gx) * DIN))[t];
  }
  __syncthreads();
  float4* ob = (float4*)(decoded + (size_t)bh * (32 * DIN));
  for (int w = 0; w < 32; ++w) {
    float sx = (w + 0.5f) * 0.125f - 0.5f;
    int x0 = (int)floorf(sx);
    float fx = sx - (float)x0;
    int x1 = min(x0 + 1, 3);
    x0 = max(x0, 0);
    float w00 = (1.f - fy) * (1.f - fx), w01 = (1.f - fy) * fx;
    float w10 = fy * (1.f - fx), w11 = fy * fx;
    float4 v00 = ((const float4*)s_y[x0])[t];
    float4 v01 = ((const float4*)s_y[x1])[t];
    float4 v10 = ((const float4*)s_y[4 + x0])[t];
    float4 v11 = ((const float4*)s_y[4 + x1])[t];
    float4 o;
    o.x = w00 * v00.x + w01 * v01.x + w10 * v10.x + w11 * v11.x;
    o.y = w00 * v00.y + w01 * v01.y + w10 * v10.y + w11 * v11.y;
    o.z = w00 * v00.z + w01 * v01.z + w10 * v10.z + w11 * v11.z;
    o.w = w00 * v00.w + w01 * v01.w + w10 * v10.w + w11 * v11.w;
    ob[(size_t)w * (DIN / 4) + t] = o;
  }
}

extern "C" void kernel_launch(void* const* d_in, const int* in_sizes, int n_in,
                              void* d_out, int out_size, void* d_ws, size_t ws_size,
                              hipStream_t stream) {
  const float* t0        = (const float*)d_in[0];
  const float* t1        = (const float*)d_in[1];
  const float* noise     = (const float*)d_in[2];
  const float* codebooks = (const float*)d_in[3];
  const float* W_in      = (const float*)d_in[4];
  const float* b_in      = (const float*)d_in[5];
  const float* W_out     = (const float*)d_in[6];
  const float* b_out     = (const float*)d_in[7];
  float* out = (float*)d_out;
  float* ws  = (float*)d_ws;

  float* pooled  = ws + WS_POOLED;   // [512,1024]
  float* Y       = ws + WS_Y;        // [512,1024]
  float* cbn     = ws + WS_CBN;      // [8192]
  float* decoded = out;
  float* perp    = out + OUT_PERP;
  float* counts  = out + OUT_COUNTS;
  float* idx_out = out + OUT_IDX;

  hipLaunchKernelGGL(k_pool_cbn, dim3(544), dim3(256), 0, stream,
                     t0, t1, codebooks, pooled, cbn, counts);
  hipLaunchKernelGGL(k_vq, dim3(128), dim3(256), 0, stream,
                     pooled, cbn, noise, codebooks, W_in, b_in, W_out, b_out,
                     Y, counts, idx_out);
  hipLaunchKernelGGL(k_decode, dim3(1025), dim3(256), 0, stream,
                     Y, counts, decoded, perp);
}

// Round 2
// 414.851 us; speedup vs baseline: 1.2497x; 1.2497x over previous
//
#include <hip/hip_runtime.h>
#include <math.h>

#define DIN  1024
#define DE   64
#define KK   8192
#define NN   512            // B*S flat rows
#define EPSF 1e-12f

// d_out layout (floats): decoded | perplexity | codebooks_used | indices
#define OUT_PERP   33554432
#define OUT_COUNTS 33554433
#define OUT_IDX    33562625

// ws layout (float offsets). Y aliases part_pool (consumed before Y written).
#define WS_PPOOL 0            // [2][512][1024] = 1,048,576 floats
#define WS_Y     0            // [512][1024]    (aliases; K2 reads ppool before K4 writes Y)
#define WS_CT    1048576      // [64][8192]     = 524,288
#define WS_WIT   1572864      // [1024][64]     = 65,536
#define WS_WOT   1638400      // [64][1024]     = 65,536
#define WS_F     1703936      // [512][64]      = 32,768
#define WS_FN    1736704      // [512]
#define WS_CBN   1737216      // [8192]
#define WS_MIN   1745408      // [512] u64 (= 1024 floats)

typedef unsigned long long ull;

// ---------------------------------------------------------------------------
// K1: blocks [0,1024): half-pool partials (n = bx>>1, half = bx&1, 32 pixels)
//     blocks [1024,1056): codebook transpose CT[d][k] + cbn + WiT/WoT chunks
//     block 1056: zero counts, init minbuf
// ---------------------------------------------------------------------------
__global__ __launch_bounds__(256) void k_prep(
    const float* __restrict__ t0, const float* __restrict__ t1,
    const float* __restrict__ codebooks,
    const float* __restrict__ W_in, const float* __restrict__ W_out,
    float* __restrict__ ws, float* __restrict__ counts)
{
  int t = threadIdx.x;
  int bx = blockIdx.x;
  if (bx < 1024) {
    int n = bx >> 1, h = bx & 1;
    int b = n >> 4, gi = (n >> 2) & 3, gj = n & 3;
    size_t base = (((size_t)b * 32 + gi * 8 + h * 4) * 32 + gj * 8) * DIN;
    const float4* p0 = (const float4*)(t0 + base) + t;
    const float4* p1 = (const float4*)(t1 + base) + t;
    float ax = 0.f, ay = 0.f, az = 0.f, aw = 0.f;
    #pragma unroll 2
    for (int r = 0; r < 4; ++r) {
      #pragma unroll
      for (int c = 0; c < 8; ++c) {
        size_t off = ((size_t)r * 32 + c) * (DIN / 4);
        float4 u = p1[off];
        float4 v = p0[off];
        ax += u.x - v.x; ay += u.y - v.y; az += u.z - v.z; aw += u.w - v.w;
      }
    }
    float4* pp4 = (float4*)(ws + WS_PPOOL);
    pp4[((size_t)h * NN + n) * (DIN / 4) + t] = make_float4(ax, ay, az, aw);
    return;
  }
  if (bx < 1056) {
    int bb = bx - 1024;          // 0..31
    // codebook transpose + norms: thread t handles codebook k
    int k = bb * 256 + t;
    const float* row = codebooks + (size_t)k * DE;
    float* CT = ws + WS_CT;
    float s = 0.f;
    #pragma unroll 8
    for (int d = 0; d < DE; ++d) {
      float v = row[d];
      CT[(size_t)d * KK + k] = v;
      s = fmaf(v, v, s);
    }
    (ws + WS_CBN)[k] = s;
    // W_in / W_out transpose chunks (2048 elements per block each)
    float* WiT = ws + WS_WIT;
    float* WoT = ws + WS_WOT;
    #pragma unroll
    for (int i = 0; i < 8; ++i) {
      int f = bb * 2048 + i * 256 + t;
      float vi = W_in[f];
      int d = f >> 10, c = f & 1023;
      WiT[c * DE + d] = vi;                 // WiT[c][d]
      float vo = W_out[f];
      int c2 = f >> 6, d2 = f & 63;
      WoT[d2 * DIN + c2] = vo;              // WoT[d][c]
    }
    return;
  }
  // init block
  for (int i = t; i < KK; i += 256) counts[i] = 0.f;
  ull* mb = (ull*)(ws + WS_MIN);
  for (int i = t; i < NN; i += 256) mb[i] = ~0ull;
}

// ---------------------------------------------------------------------------
// K2: encode. block n: pooled row = (pp[0]+pp[1])/64 ; F[n][d] = dot + b_in
// ---------------------------------------------------------------------------
__global__ __launch_bounds__(256) void k_enc(
    const float* __restrict__ ws_ro, const float* __restrict__ b_in,
    float* __restrict__ ws)
{
  __shared__ float s_pool[DIN];
  __shared__ float s_part[4][DE];
  int t = threadIdx.x;
  int n = blockIdx.x;
  const float4* pp4 = (const float4*)(ws_ro + WS_PPOOL);
  float4 a = pp4[(size_t)n * (DIN / 4) + t];
  float4 b = pp4[((size_t)NN + n) * (DIN / 4) + t];
  const float inv = 1.f / 64.f;
  ((float4*)s_pool)[t] = make_float4((a.x + b.x) * inv, (a.y + b.y) * inv,
                                     (a.z + b.z) * inv, (a.w + b.w) * inv);
  __syncthreads();
  int w = t >> 6, lane = t & 63;
  const float* WiT = ws_ro + WS_WIT;
  float acc = 0.f;
  #pragma unroll 4
  for (int i = 0; i < 256; ++i) {
    float wv = WiT[(size_t)(w * 256 + i) * DE + lane];   // coalesced 256B/wave
    acc = fmaf(wv, s_pool[w * 256 + i], acc);            // LDS broadcast
  }
  s_part[w][lane] = acc;
  __syncthreads();
  if (t < DE) {
    float f = s_part[0][t] + s_part[1][t] + s_part[2][t] + s_part[3][t] + b_in[t];
    (ws + WS_F)[(size_t)n * DE + t] = f;
    float sq = f * f;
    #pragma unroll
    for (int m = 32; m > 0; m >>= 1) sq += __shfl_xor(sq, m, 64);
    if (t == 0) (ws + WS_FN)[n] = sq;
  }
}

// ---------------------------------------------------------------------------
// K3: distance scan. 1024 blocks = 128 rowgroups x 8 K-chunks.
//     thread: 4 codebooks (one float4 group along k), 4 rows -> 16 accums.
// ---------------------------------------------------------------------------
__device__ __forceinline__ void upd_min(ull& best, float e, int k) {
  e = fmaxf(e, 0.f);
  ull p = ((ull)__float_as_uint(e) << 32) | (unsigned int)k;
  best = (p < best) ? p : best;
}

__global__ __launch_bounds__(256) void k_dist(
    const float* __restrict__ ws_ro, float* __restrict__ ws)
{
  __shared__ float4 s_f4[4][16];
  __shared__ float s_fn[4];
  __shared__ ull s_min[4];
  int t = threadIdx.x;
  int rg = blockIdx.x & 127, kc = blockIdx.x >> 7;
  int n0 = rg * 4;
  if (t < 64) {
    int r = t >> 4, g = t & 15;
    s_f4[r][g] = ((const float4*)(ws_ro + WS_F + (size_t)(n0 + r) * DE))[g];
  }
  if (t < 4) { s_fn[t] = (ws_ro + WS_FN)[n0 + t]; s_min[t] = ~0ull; }
  __syncthreads();

  int kq = (kc << 8) + t;        // float4 group index along k: 0..2047
  int k0 = kq * 4;
  const float4* CT4 = (const float4*)(ws_ro + WS_CT);
  float4 acc0 = {0, 0, 0, 0}, acc1 = {0, 0, 0, 0}, acc2 = {0, 0, 0, 0}, acc3 = {0, 0, 0, 0};
  #pragma unroll 4
  for (int g = 0; g < 16; ++g) {
    float fa0[4], fa1[4], fa2[4], fa3[4];
    *(float4*)fa0 = s_f4[0][g];
    *(float4*)fa1 = s_f4[1][g];
    *(float4*)fa2 = s_f4[2][g];
    *(float4*)fa3 = s_f4[3][g];
    #pragma unroll
    for (int j = 0; j < 4; ++j) {
      float4 ct = CT4[(size_t)(4 * g + j) * (KK / 4) + kq];  // coalesced 1KB/wave
      acc0.x = fmaf(fa0[j], ct.x, acc0.x); acc0.y = fmaf(fa0[j], ct.y, acc0.y);
      acc0.z = fmaf(fa0[j], ct.z, acc0.z); acc0.w = fmaf(fa0[j], ct.w, acc0.w);
      acc1.x = fmaf(fa1[j], ct.x, acc1.x); acc1.y = fmaf(fa1[j], ct.y, acc1.y);
      acc1.z = fmaf(fa1[j], ct.z, acc1.z); acc1.w = fmaf(fa1[j], ct.w, acc1.w);
      acc2.x = fmaf(fa2[j], ct.x, acc2.x); acc2.y = fmaf(fa2[j], ct.y, acc2.y);
      acc2.z = fmaf(fa2[j], ct.z, acc2.z); acc2.w = fmaf(fa2[j], ct.w, acc2.w);
      acc3.x = fmaf(fa3[j], ct.x, acc3.x); acc3.y = fmaf(fa3[j], ct.y, acc3.y);
      acc3.z = fmaf(fa3[j], ct.z, acc3.z); acc3.w = fmaf(fa3[j], ct.w, acc3.w);
    }
  }
  float4 cn = ((const float4*)(ws_ro + WS_CBN))[kq];
  ull b0 = ~0ull, b1 = ~0ull, b2 = ~0ull, b3 = ~0ull;
  float fn0 = s_fn[0], fn1 = s_fn[1], fn2 = s_fn[2], fn3 = s_fn[3];
  upd_min(b0, fmaf(-2.f, acc0.x, fn0 + cn.x), k0);
  upd_min(b0, fmaf(-2.f, acc0.y, fn0 + cn.y), k0 + 1);
  upd_min(b0, fmaf(-2.f, acc0.z, fn0 + cn.z), k0 + 2);
  upd_min(b0, fmaf(-2.f, acc0.w, fn0 + cn.w), k0 + 3);
  upd_min(b1, fmaf(-2.f, acc1.x, fn1 + cn.x), k0);
  upd_min(b1, fmaf(-2.f, acc1.y, fn1 + cn.y), k0 + 1);
  upd_min(b1, fmaf(-2.f, acc1.z, fn1 + cn.z), k0 + 2);
  upd_min(b1, fmaf(-2.f, acc1.w, fn1 + cn.w), k0 + 3);
  upd_min(b2, fmaf(-2.f, acc2.x, fn2 + cn.x), k0);
  upd_min(b2, fmaf(-2.f, acc2.y, fn2 + cn.y), k0 + 1);
  upd_min(b2, fmaf(-2.f, acc2.z, fn2 + cn.z), k0 + 2);
  upd_min(b2, fmaf(-2.f, acc2.w, fn2 + cn.w), k0 + 3);
  upd_min(b3, fmaf(-2.f, acc3.x, fn3 + cn.x), k0);
  upd_min(b3, fmaf(-2.f, acc3.y, fn3 + cn.y), k0 + 1);
  upd_min(b3, fmaf(-2.f, acc3.z, fn3 + cn.z), k0 + 2);
  upd_min(b3, fmaf(-2.f, acc3.w, fn3 + cn.w), k0 + 3);
  atomicMin(&s_min[0], b0);
  atomicMin(&s_min[1], b1);
  atomicMin(&s_min[2], b2);
  atomicMin(&s_min[3], b3);
  __syncthreads();
  if (t < 4) atomicMin((ull*)(ws + WS_MIN) + n0 + t, s_min[t]);
}

// ---------------------------------------------------------------------------
// K4: NSVQ + project_out. block n: wave0 does NSVQ, all threads project.
// ---------------------------------------------------------------------------
__global__ __launch_bounds__(256) void k_nsvq_out(
    const float* __restrict__ ws_ro, const float* __restrict__ noise,
    const float* __restrict__ codebooks, const float* __restrict__ b_out,
    float* __restrict__ ws, float* __restrict__ counts,
    float* __restrict__ idx_out)
{
  __shared__ float s_q[DE];
  int t = threadIdx.x;
  int n = blockIdx.x;
  if (t < DE) {
    ull m = ((const ull*)(ws_ro + WS_MIN))[n];
    unsigned idx = (unsigned)(m & 0xffffffffu);
    float f = (ws_ro + WS_F)[(size_t)n * DE + t];
    float hv = codebooks[(size_t)idx * DE + t];
    float nz = noise[(size_t)n * DE + t];
    float df = f - hv;
    float sd = df * df, sn = nz * nz;
    #pragma unroll
    for (int m2 = 32; m2 > 0; m2 >>= 1) {
      sd += __shfl_xor(sd, m2, 64);
      sn += __shfl_xor(sn, m2, 64);
    }
    float scale = sqrtf(sd) / (sqrtf(sn) + EPSF);
    s_q[t] = fmaf(scale, nz, f);
    if (t == 0) {
      idx_out[n] = (float)idx;
      atomicAdd(&counts[idx], 1.0f);
    }
  }
  __syncthreads();
  const float4* WoT4 = (const float4*)(ws_ro + WS_WOT);
  float4 acc = {0, 0, 0, 0};
  #pragma unroll 4
  for (int i = 0; i < DE; ++i) {
    float q = s_q[i];
    float4 w = WoT4[(size_t)i * (DIN / 4) + t];   // coalesced
    acc.x = fmaf(q, w.x, acc.x); acc.y = fmaf(q, w.y, acc.y);
    acc.z = fmaf(q, w.z, acc.z); acc.w = fmaf(q, w.w, acc.w);
  }
  float4 bo = ((const float4*)b_out)[t];
  acc.x += bo.x; acc.y += bo.y; acc.z += bo.z; acc.w += bo.w;
  ((float4*)(ws + WS_Y))[(size_t)n * (DIN / 4) + t] = acc;
}

// ---------------------------------------------------------------------------
// K5: bilinear upsample + perplexity (block 1024)
// ---------------------------------------------------------------------------
__global__ __launch_bounds__(256) void k_decode(
    const float* __restrict__ ws_ro, const float* __restrict__ counts,
    float* __restrict__ decoded, float* __restrict__ perp)
{
  int t = threadIdx.x;
  if (blockIdx.x == 1024) {
    __shared__ float red[256];
    float s = 0.f;
    for (int k = t; k < KK; k += 256) {
      float p = counts[k] * (1.0f / 512.0f);
      s += p * logf(p + EPSF);
    }
    red[t] = s;
    __syncthreads();
    for (int o = 128; o > 0; o >>= 1) {
      if (t < o) red[t] += red[t + o];
      __syncthreads();
    }
    if (t == 0) perp[0] = expf(-red[0]);
    return;
  }
  __shared__ float s_y[8][DIN];  // rows {y0,y1} x gx{0..3} : 32 KB
  const float* Y = ws_ro + WS_Y;
  int bh = blockIdx.x;
  int b = bh >> 5, h = bh & 31;
  float sy = (h + 0.5f) * 0.125f - 0.5f;
  int y0 = (int)floorf(sy);
  float fy = sy - (float)y0;
  int y1 = min(y0 + 1, 3);
  y0 = max(y0, 0);
  #pragma unroll
  for (int gx = 0; gx < 4; ++gx) {
    ((float4*)s_y[gx])[t]     = ((const float4*)(Y + (size_t)(b * 16 + y0 * 4 + gx) * DIN))[t];
    ((float4*)s_y[4 + gx])[t] = ((const float4*)(Y + (size_t)(b * 16 + y1 * 4 + gx) * DIN))[t];
  }
  __syncthreads();
  float4* ob = (float4*)(decoded + (size_t)bh * (32 * DIN));
  for (int w = 0; w < 32; ++w) {
    float sx = (w + 0.5f) * 0.125f - 0.5f;
    int x0 = (int)floorf(sx);
    float fx = sx - (float)x0;
    int x1 = min(x0 + 1, 3);
    x0 = max(x0, 0);
    float w00 = (1.f - fy) * (1.f - fx), w01 = (1.f - fy) * fx;
    float w10 = fy * (1.f - fx), w11 = fy * fx;
    float4 v00 = ((const float4*)s_y[x0])[t];
    float4 v01 = ((const float4*)s_y[x1])[t];
    float4 v10 = ((const float4*)s_y[4 + x0])[t];
    float4 v11 = ((const float4*)s_y[4 + x1])[t];
    float4 o;
    o.x = w00 * v00.x + w01 * v01.x + w10 * v10.x + w11 * v11.x;
    o.y = w00 * v00.y + w01 * v01.y + w10 * v10.y + w11 * v11.y;
    o.z = w00 * v00.z + w01 * v01.z + w10 * v10.z + w11 * v11.z;
    o.w = w00 * v00.w + w01 * v01.w + w10 * v10.w + w11 * v11.w;
    ob[(size_t)w * (DIN / 4) + t] = o;
  }
}

extern "C" void kernel_launch(void* const* d_in, const int* in_sizes, int n_in,
                              void* d_out, int out_size, void* d_ws, size_t ws_size,
                              hipStream_t stream) {
  const float* t0        = (const float*)d_in[0];
  const float* t1        = (const float*)d_in[1];
  const float* noise     = (const float*)d_in[2];
  const float* codebooks = (const float*)d_in[3];
  const float* W_in      = (const float*)d_in[4];
  const float* b_in      = (const float*)d_in[5];
  const float* W_out     = (const float*)d_in[6];
  const float* b_out     = (const float*)d_in[7];
  float* out = (float*)d_out;
  float* ws  = (float*)d_ws;

  float* decoded = out;
  float* perp    = out + OUT_PERP;
  float* counts  = out + OUT_COUNTS;
  float* idx_out = out + OUT_IDX;

  hipLaunchKernelGGL(k_prep, dim3(1057), dim3(256), 0, stream,
                     t0, t1, codebooks, W_in, W_out, ws, counts);
  hipLaunchKernelGGL(k_enc, dim3(512), dim3(256), 0, stream,
                     ws, b_in, ws);
  hipLaunchKernelGGL(k_dist, dim3(1024), dim3(256), 0, stream,
                     ws, ws);
  hipLaunchKernelGGL(k_nsvq_out, dim3(512), dim3(256), 0, stream,
                     ws, noise, codebooks, b_out, ws, counts, idx_out);
  hipLaunchKernelGGL(k_decode, dim3(1025), dim3(256), 0, stream,
                     ws, counts, decoded, perp);
}